// Round 5
// baseline (111.713 us; speedup 1.0000x reference)
//
#include <hip/hip_runtime.h>

// Problem: B,H,W,D = 64,32,32,64 ; K=1024 ; N = 65536
#define NPTS   65536
#define DDIM   64
#define KCODES 1024
#define QOUT_ELEMS (NPTS * DDIM)

typedef _Float16 half8    __attribute__((ext_vector_type(8)));
typedef float    floatx16 __attribute__((ext_vector_type(16)));
typedef unsigned int uint;

#define AS1 __attribute__((address_space(1)))
#define AS3 __attribute__((address_space(3)))

// ws: ehp [0,128K) chunk-major f16 | elp [128K,256K) | e2 packed [256K,260K)
// scr: per-(point,khalf) float2 candidates at 264K (1 MB)
#define WS_EHP   0
#define WS_ELP   (128*1024)
#define WS_E2    (256*1024)
#define WS_SCR   (264*1024)

union H8U { half8 v; uint u[4]; };

static __device__ __forceinline__ void gl_lds16(const void* g, void* l) {
    __builtin_amdgcn_global_load_lds((const AS1 uint*)g, (AS3 uint*)l, 16, 0, 0);
}

// ---------------------------------------------------------------------------
// Prep (verified r4): one wave per code. fp16 hi/lo split, CHUNK-MAJOR tiles:
// tile T=k>>5, chunk j=d>>3, c=k&31: byte off = T*4096 + j*512 + c*16 + (d&7)*2
// Plus packed (e2h,e2l) per code.
// ---------------------------------------------------------------------------
__global__ void eprep_kernel(const float* __restrict__ emb, char* __restrict__ ws) {
    const int tid = threadIdx.x;
    const int w = tid >> 6, d = tid & 63;
    const int k = blockIdx.x * 4 + w;
    float v = emb[(size_t)k * DDIM + d];
    _Float16 h = (_Float16)v;
    _Float16 l = (_Float16)(v - (float)h);
    size_t off = (size_t)(k >> 5) * 4096 + (size_t)(d >> 3) * 512
               + (size_t)(k & 31) * 16 + (size_t)(d & 7) * 2;
    *(_Float16*)(ws + WS_EHP + off) = h;
    *(_Float16*)(ws + WS_ELP + off) = l;
    float s = v * v;
    #pragma unroll
    for (int m = 1; m < 64; m <<= 1) s += __shfl_xor(s, m, 64);
    if (d == 0) {
        _Float16 e2h = (_Float16)s;
        _Float16 e2l = (_Float16)(s - (float)e2h);
        unsigned short hb = *(unsigned short*)&e2h;
        unsigned short lb = *(unsigned short*)&e2l;
        ((uint*)(ws + WS_E2))[k] = (uint)hb | ((uint)lb << 16);
    }
}

// ---------------------------------------------------------------------------
// Main: grid 512 = (pgrp 256) x (khalf 2). Block 256 thr = 4 waves.
// Wave w owns M=64 points: two 32-point sets (pgrp*256 + w*64 + set*32 + col),
// over its 512-code K-half (16 tiles of 32). Each staged B-fragment feeds
// BOTH sets' MFMAs (halves LDS read demand vs r4). Double-buffered 2-tile
// staging: one barrier per 2 tiles, 832 MFMA-cyc between barriers, prefetch
// issued right after the barrier so the next drain is cheap.
// Layouts (verified r2/r4): A[m][k]: m=lane&31,k=sel8*8+j; B same (n=lane&31);
// C/D: col=lane&31, row=(r&3)+8*(r>>2)+4*sel8.
// ---------------------------------------------------------------------------
__global__ __launch_bounds__(256, 2) void vq_kernel(
    const float* __restrict__ z,
    const char* __restrict__ ws_c,
    float2* __restrict__ scr)
{
    const int tid  = threadIdx.x;
    const int lane = tid & 63;
    const int w    = __builtin_amdgcn_readfirstlane(tid >> 6);
    const int col  = lane & 31;
    const int sel8 = lane >> 5;
    const int pgrp  = blockIdx.x >> 1;
    const int khalf = blockIdx.x & 1;

    // double buffer: [buf][ eh q0 | eh q1 | el q0 | el q1 ] = 16 KB each
    __shared__ uint4 ldsbuf[2][1024];
    __shared__ uint  lds_e2[512];    // packed (e2h,e2l), this khalf's 512 codes

    // ---- A fragments: a = -2 z[pt], hi/lo fp16, for both point sets ----
    half8 ah[2][4], al[2][4];
    #pragma unroll
    for (int set = 0; set < 2; ++set) {
        const int pt = pgrp * 256 + w * 64 + set * 32 + col;
        const float* zrow = z + (size_t)pt * DDIM + sel8 * 8;
        #pragma unroll
        for (int ks = 0; ks < 4; ++ks) {
            float4 u0 = *(const float4*)(zrow + ks * 16);
            float4 u1 = *(const float4*)(zrow + ks * 16 + 4);
            float tv[8] = {u0.x, u0.y, u0.z, u0.w, u1.x, u1.y, u1.z, u1.w};
            #pragma unroll
            for (int j = 0; j < 8; ++j) {
                float a = -2.0f * tv[j];
                _Float16 hh = (_Float16)a;
                ah[set][ks][j] = hh;
                al[set][ks][j] = (_Float16)(a - (float)hh);
            }
        }
    }
    // e2-step A: ones ONLY at k=0,1 (sel8==0 lanes) — r3 double-count fix.
    half8 ahE;
    { H8U t0; t0.u[0] = (sel8 == 0) ? 0x3C003C00u : 0u;
      t0.u[1] = t0.u[2] = t0.u[3] = 0u; ahE = t0.v; }

    // ---- prologue staging: e2 (waves 0,1) + step 0 tiles ----
    if (w < 2)
        gl_lds16(ws_c + WS_E2 + khalf * 2048 + w * 1024 + lane * 16,
                 (char*)lds_e2 + w * 1024);
    {
        const int opnd = w >> 1, q = w & 1;   // wave -> (eh/el, tile-in-step)
        const char* src = ws_c + (opnd ? WS_ELP : WS_EHP)
                        + (size_t)(khalf * 16 + q) * 4096 + lane * 16;
        char* dst = (char*)ldsbuf[0] + (opnd * 8192 + q * 4096);
        #pragma unroll
        for (int i = 0; i < 4; ++i)
            gl_lds16(src + i * 1024, dst + i * 1024);
    }

    const floatx16 zeroC = {};
    float best[2][16];
    int   bt[2][16];
    #pragma unroll
    for (int set = 0; set < 2; ++set)
        #pragma unroll
        for (int r = 0; r < 16; ++r) { best[set][r] = 3.4e38f; bt[set][r] = 0; }

    for (int s = 0; s < 8; ++s) {
        __syncthreads();   // step-s stage landed; other buffer free for reuse
        if (s < 7) {       // prefetch step s+1 into the other buffer
            const int opnd = w >> 1, q = w & 1;
            const char* src = ws_c + (opnd ? WS_ELP : WS_EHP)
                            + (size_t)(khalf * 16 + (s + 1) * 2 + q) * 4096 + lane * 16;
            char* dst = (char*)ldsbuf[(s + 1) & 1] + (opnd * 8192 + q * 4096);
            #pragma unroll
            for (int i = 0; i < 4; ++i)
                gl_lds16(src + i * 1024, dst + i * 1024);
        }
        const char* buf = (const char*)ldsbuf[s & 1];

        #pragma unroll
        for (int q = 0; q < 2; ++q) {
            const int tg = s * 2 + q;          // tile index within khalf, 0..15
            const char* ehb = buf + q * 4096 + sel8 * 512 + col * 16;
            const char* elb = ehb + 8192;
            half8 bh[4], bl[4];
            #pragma unroll
            for (int ks = 0; ks < 4; ++ks) {
                bh[ks] = *(const half8*)(ehb + ks * 1024);
                bl[ks] = *(const half8*)(elb + ks * 1024);
            }
            half8 bhE;
            { H8U u; u.u[0] = lds_e2[tg * 32 + col];
              u.u[1] = u.u[2] = u.u[3] = 0u; bhE = u.v; }

            floatx16 a0, a1;   // two independent 13-MFMA chains (sets 0,1)
            a0 = __builtin_amdgcn_mfma_f32_32x32x16_f16(ah[0][0], bh[0], zeroC, 0, 0, 0);
            a1 = __builtin_amdgcn_mfma_f32_32x32x16_f16(ah[1][0], bh[0], zeroC, 0, 0, 0);
            a0 = __builtin_amdgcn_mfma_f32_32x32x16_f16(ah[0][1], bh[1], a0, 0, 0, 0);
            a1 = __builtin_amdgcn_mfma_f32_32x32x16_f16(ah[1][1], bh[1], a1, 0, 0, 0);
            a0 = __builtin_amdgcn_mfma_f32_32x32x16_f16(ah[0][2], bh[2], a0, 0, 0, 0);
            a1 = __builtin_amdgcn_mfma_f32_32x32x16_f16(ah[1][2], bh[2], a1, 0, 0, 0);
            a0 = __builtin_amdgcn_mfma_f32_32x32x16_f16(ah[0][3], bh[3], a0, 0, 0, 0);
            a1 = __builtin_amdgcn_mfma_f32_32x32x16_f16(ah[1][3], bh[3], a1, 0, 0, 0);
            a0 = __builtin_amdgcn_mfma_f32_32x32x16_f16(ahE, bhE, a0, 0, 0, 0);
            a1 = __builtin_amdgcn_mfma_f32_32x32x16_f16(ahE, bhE, a1, 0, 0, 0);
            a0 = __builtin_amdgcn_mfma_f32_32x32x16_f16(ah[0][0], bl[0], a0, 0, 0, 0);
            a1 = __builtin_amdgcn_mfma_f32_32x32x16_f16(ah[1][0], bl[0], a1, 0, 0, 0);
            a0 = __builtin_amdgcn_mfma_f32_32x32x16_f16(ah[0][1], bl[1], a0, 0, 0, 0);
            a1 = __builtin_amdgcn_mfma_f32_32x32x16_f16(ah[1][1], bl[1], a1, 0, 0, 0);
            a0 = __builtin_amdgcn_mfma_f32_32x32x16_f16(ah[0][2], bl[2], a0, 0, 0, 0);
            a1 = __builtin_amdgcn_mfma_f32_32x32x16_f16(ah[1][2], bl[2], a1, 0, 0, 0);
            a0 = __builtin_amdgcn_mfma_f32_32x32x16_f16(ah[0][3], bl[3], a0, 0, 0, 0);
            a1 = __builtin_amdgcn_mfma_f32_32x32x16_f16(ah[1][3], bl[3], a1, 0, 0, 0);
            a0 = __builtin_amdgcn_mfma_f32_32x32x16_f16(al[0][0], bh[0], a0, 0, 0, 0);
            a1 = __builtin_amdgcn_mfma_f32_32x32x16_f16(al[1][0], bh[0], a1, 0, 0, 0);
            a0 = __builtin_amdgcn_mfma_f32_32x32x16_f16(al[0][1], bh[1], a0, 0, 0, 0);
            a1 = __builtin_amdgcn_mfma_f32_32x32x16_f16(al[1][1], bh[1], a1, 0, 0, 0);
            a0 = __builtin_amdgcn_mfma_f32_32x32x16_f16(al[0][2], bh[2], a0, 0, 0, 0);
            a1 = __builtin_amdgcn_mfma_f32_32x32x16_f16(al[1][2], bh[2], a1, 0, 0, 0);
            a0 = __builtin_amdgcn_mfma_f32_32x32x16_f16(al[0][3], bh[3], a0, 0, 0, 0);
            a1 = __builtin_amdgcn_mfma_f32_32x32x16_f16(al[1][3], bh[3], a1, 0, 0, 0);

            #pragma unroll
            for (int r = 0; r < 16; ++r) {
                bool c0 = a0[r] < best[0][r];
                best[0][r] = c0 ? a0[r] : best[0][r];
                bt[0][r]   = c0 ? tg    : bt[0][r];
                bool c1 = a1[r] < best[1][r];
                best[1][r] = c1 ? a1[r] : best[1][r];
                bt[1][r]   = c1 ? tg    : bt[1][r];
            }
        }
    }

    // ---- per-set: codes, butterfly argmin over 32 cols, emit candidates ----
    #pragma unroll
    for (int set = 0; set < 2; ++set) {
        int code[16];
        #pragma unroll
        for (int r = 0; r < 16; ++r)
            code[r] = khalf * 512 + bt[set][r] * 32 + col;
        #pragma unroll
        for (int m = 1; m < 32; m <<= 1) {
            #pragma unroll
            for (int r = 0; r < 16; ++r) {
                float ov = __shfl_xor(best[set][r], m, 64);
                int   oc = __shfl_xor(code[r], m, 64);
                bool c = (ov < best[set][r]) || (ov == best[set][r] && oc < code[r]);
                best[set][r] = c ? ov : best[set][r];
                code[r]      = c ? oc : code[r];
            }
        }
        if (col == 0) {   // lanes 0 / 32 hold rows 4*sel8 pattern
            #pragma unroll
            for (int r = 0; r < 16; ++r) {
                int row = (r & 3) + 8 * (r >> 2) + 4 * sel8;
                int p = pgrp * 256 + w * 64 + set * 32 + row;
                scr[(size_t)p * 2 + khalf] =
                    make_float2(best[set][r], __int_as_float(code[r]));
            }
        }
    }
}

// ---------------------------------------------------------------------------
// Merge khalf candidates; gather quantized + write indices (verified r2).
// ---------------------------------------------------------------------------
__global__ void merge_gather_kernel(const float* __restrict__ emb,
                                    const float2* __restrict__ scr,
                                    float* __restrict__ out)
{
    int f = blockIdx.x * 256 + threadIdx.x;
    int pt = f >> 4, d4 = f & 15;
    float2 c0 = scr[(size_t)pt * 2];
    float2 c1 = scr[(size_t)pt * 2 + 1];
    int i0 = __float_as_int(c0.y), i1 = __float_as_int(c1.y);
    int idx = (c1.x < c0.x) ? i1 : i0;   // khalf1 codes higher: strict <
    ((float4*)out)[(size_t)pt * 16 + d4] = ((const float4*)emb)[(size_t)idx * 16 + d4];
    if (d4 == 0) out[QOUT_ELEMS + pt] = (float)idx;
}

extern "C" void kernel_launch(void* const* d_in, const int* in_sizes, int n_in,
                              void* d_out, int out_size, void* d_ws, size_t ws_size,
                              hipStream_t stream) {
    const float* z   = (const float*)d_in[0];
    const float* emb = (const float*)d_in[1];
    float* out = (float*)d_out;
    char* ws = (char*)d_ws;
    float2* scr = (float2*)(ws + WS_SCR);

    eprep_kernel<<<KCODES / 4, 256, 0, stream>>>(emb, ws);
    vq_kernel<<<512, 256, 0, stream>>>(z, ws, scr);
    merge_gather_kernel<<<NPTS * 16 / 256, 256, 0, stream>>>(emb, scr, out);
}